// Round 2
// baseline (205.618 us; speedup 1.0000x reference)
//
#include <hip/hip_runtime.h>
#include <hip/hip_bf16.h>

typedef __attribute__((ext_vector_type(8))) short bf16x8;
typedef __attribute__((ext_vector_type(4))) float f32x4;

#define LDSG(g, l) __builtin_amdgcn_global_load_lds(                      \
    (const __attribute__((address_space(1))) void*)(g),                   \
    (__attribute__((address_space(3))) void*)(l), 16, 0, 0)

#define LOG2E 1.44269504088896f
#define RELSC 0.180336880111112f   /* 0.125 * log2(e) */

// ---------------- kernel 1: fp32 -> bf16 convert (hidden + Wq|Wk|Wv) --------
__global__ __launch_bounds__(256) void cvt_kernel(
    const float* __restrict__ hs,
    const float* __restrict__ wq, const float* __restrict__ wk,
    const float* __restrict__ wv,
    __hip_bfloat16* __restrict__ hbf, __hip_bfloat16* __restrict__ wbf)
{
  const int NH = (4 * 1024 * 1024) / 4;   // hidden quads
  const int NW = (1024 * 1024) / 4;       // per-W quads
  int i = blockIdx.x * 256 + threadIdx.x; // exact grid: NH + 3*NW quads
  float4 v;
  __hip_bfloat16* dst;
  if (i < NH) {
    v = ((const float4*)hs)[i];
    dst = hbf + (size_t)i * 4;
  } else {
    int j = i - NH;
    int which = j / NW, r = j - which * NW;
    const float* src = which == 0 ? wq : (which == 1 ? wk : wv);
    v = ((const float4*)src)[r];
    dst = wbf + (size_t)j * 4;
  }
  union { ushort4 u; __hip_bfloat16 b[4]; } o;
  o.b[0] = __float2bfloat16(v.x);
  o.b[1] = __float2bfloat16(v.y);
  o.b[2] = __float2bfloat16(v.z);
  o.b[3] = __float2bfloat16(v.w);
  *((ushort4*)dst) = o.u;
}

// ---------------- kernel 2: QKV GEMM  C[4096][3072] = A[4096][1024] @ W^T ---
// q scaled by 0.125*log2e and stored [b,h,s,d]; k stored [b,h,s,d];
// v stored TRANSPOSED [b,h,d,s] so attention can stage V^T via LDSG.
__global__ __launch_bounds__(256) void qkv_gemm(
    const __hip_bfloat16* __restrict__ A,  // [4096][1024]
    const __hip_bfloat16* __restrict__ W,  // [3072][1024] (q,k,v stacked)
    const float* __restrict__ bq, const float* __restrict__ bk,
    const float* __restrict__ bv,
    __hip_bfloat16* __restrict__ qo, __hip_bfloat16* __restrict__ ko,
    __hip_bfloat16* __restrict__ vo)
{
  const int K = 1024;
  __shared__ __hip_bfloat16 As[128 * 64];
  __shared__ __hip_bfloat16 Bs[128 * 64];
  const int bid = blockIdx.x;
  const int bm = bid & 31, bn = bid >> 5;
  const int m0 = bm * 128, n0 = bn * 128;
  const int tid = threadIdx.x, wid = tid >> 6, lane = tid & 63;
  const int wm = wid >> 1, wn = wid & 1;

  f32x4 acc[4][4] = {};

  const int srow = lane >> 3;              // 0..7 (row within 8-row group)
  const int schunk = (lane & 7) ^ srow;    // swizzled 16B-chunk in row

  for (int k0 = 0; k0 < K; k0 += 64) {
#pragma unroll
    for (int p = 0; p < 4; ++p) {
      int r = (wid * 4 + p) * 8 + srow;    // 0..127
      LDSG(&A[(size_t)(m0 + r) * K + k0 + schunk * 8], &As[(wid * 4 + p) * 512]);
      LDSG(&W[(size_t)(n0 + r) * K + k0 + schunk * 8], &Bs[(wid * 4 + p) * 512]);
    }
    __syncthreads();
#pragma unroll
    for (int ks = 0; ks < 2; ++ks) {
      bf16x8 af[4], bfr[4];
#pragma unroll
      for (int mi = 0; mi < 4; ++mi) {
        int row = wm * 64 + mi * 16 + (lane & 15);
        int slot = (ks * 4 + (lane >> 4)) ^ (lane & 7);
        af[mi] = *(const bf16x8*)((const char*)As + row * 128 + slot * 16);
      }
#pragma unroll
      for (int ni = 0; ni < 4; ++ni) {
        int row = wn * 64 + ni * 16 + (lane & 15);
        int slot = (ks * 4 + (lane >> 4)) ^ (lane & 7);
        bfr[ni] = *(const bf16x8*)((const char*)Bs + row * 128 + slot * 16);
      }
#pragma unroll
      for (int mi = 0; mi < 4; ++mi)
#pragma unroll
        for (int ni = 0; ni < 4; ++ni)
          acc[mi][ni] = __builtin_amdgcn_mfma_f32_16x16x32_bf16(
              af[mi], bfr[ni], acc[mi][ni], 0, 0, 0);
    }
    __syncthreads();
  }

  // epilogue. C/D layout: col = lane&15, row = (lane>>4)*4+j.
#pragma unroll
  for (int ni = 0; ni < 4; ++ni) {
    int n = n0 + wn * 64 + ni * 16 + (lane & 15);
    int which = n >> 10;         // 0=q 1=k 2=v (uniform per block)
    int h = (n >> 6) & 15;
    int d = n & 63;
    const float* bias = which == 0 ? bq : (which == 1 ? bk : bv);
    float bval = bias[n & 1023];
    if (which == 2) {
      // v transposed: vo[(bh*64+d)*1024 + s], 4 consecutive s -> ushort4
#pragma unroll
      for (int mi = 0; mi < 4; ++mi) {
        int m = m0 + wm * 64 + mi * 16 + (lane >> 4) * 4;
        int b = m >> 10, s = m & 1023;
        union { ushort4 u; __hip_bfloat16 bb[4]; } o;
#pragma unroll
        for (int j = 0; j < 4; ++j)
          o.bb[j] = __float2bfloat16(acc[mi][ni][j] + bval);
        *(ushort4*)&vo[((size_t)((b * 16 + h) * 64 + d) << 10) + s] = o.u;
      }
    } else {
      __hip_bfloat16* dst = which == 0 ? qo : ko;
      float scale = (which == 0) ? RELSC : 1.0f;  // q pre-scaled by inv_sqrt_d*log2e
#pragma unroll
      for (int mi = 0; mi < 4; ++mi) {
#pragma unroll
        for (int j = 0; j < 4; ++j) {
          int m = m0 + wm * 64 + mi * 16 + (lane >> 4) * 4 + j;
          int b = m >> 10, s = m & 1023;
          float val = (acc[mi][ni][j] + bval) * scale;
          dst[(((size_t)(b * 16 + h) << 10) + s) * 64 + d] = __float2bfloat16(val);
        }
      }
    }
  }
}

// ---------------- kernel 3: flash attention, swapped QK^T -------------------
// grid: 1024 = 64 bh x 16 q-tiles of 64 rows; 4 waves, wave owns 16 q-rows.
// Scores computed transposed (mfma(K,Q)): lane holds S^T[k=ct*16+lg*4+j][q].
// rel/mask loads are float4, softmax stats are lane-scalar, PV = V^T P^T.
__global__ __launch_bounds__(256, 3) void attn_kernel(
    const __hip_bfloat16* __restrict__ qg, const __hip_bfloat16* __restrict__ kg,
    const __hip_bfloat16* __restrict__ vtg,
    const float* __restrict__ rel1, const float* __restrict__ rel2,
    const float* __restrict__ mask, float* __restrict__ out)
{
  __shared__ __hip_bfloat16 Ks[2][64 * 64];
  __shared__ __hip_bfloat16 Vts[2][64 * 64];
  __shared__ __hip_bfloat16 Ps[4][16 * 64];

  const int bid = blockIdx.x;
  const int bh = bid & 63, qt = bid >> 6;   // bid%8==bh%8 -> same-bh same XCD
  const int b = bh >> 4, h = bh & 15;
  const int tid = threadIdx.x, wid = tid >> 6, lane = tid & 63;
  const int lg = lane >> 4, ln15 = lane & 15;

  const size_t kvbase = (size_t)bh << 16;
  const int q0 = qt * 64 + wid * 16;

  // Q as B-operand fragment: col=lane&15=q, contraction d=lg*8+jj (+32 per ks)
  bf16x8 qf[2];
  qf[0] = *(const bf16x8*)&qg[kvbase + (size_t)(q0 + ln15) * 64 + lg * 8];
  qf[1] = *(const bf16x8*)&qg[kvbase + (size_t)(q0 + ln15) * 64 + 32 + lg * 8];

  f32x4 accO[4] = {};
  float mrun = -1e30f, lrun = 0.f;

  const int srow = lane >> 3, sc8 = lane & 7;
  const float* relp1 = rel1 + ((size_t)bh << 20) + (size_t)(q0 + ln15) * 1024;
  const float* relp2 = rel2 + ((size_t)bh << 20) + (size_t)(q0 + ln15) * 1024;
  const float* maskp = mask + ((size_t)b << 10);

  float4 ra[2][2][4];   // [buf][rel1/2][ct] — indices compile-time constant

#define REL_LOAD(BUF, KB) do {                                              \
    _Pragma("unroll") for (int ct = 0; ct < 4; ++ct) {                      \
      ra[BUF][0][ct] = *(const float4*)&relp1[(KB) + ct * 16 + lg * 4];     \
      ra[BUF][1][ct] = *(const float4*)&relp2[(KB) + ct * 16 + lg * 4];     \
    } } while (0)

#define STAGE(BUF, KB) do {                                                 \
    _Pragma("unroll") for (int pp = 0; pp < 2; ++pp) {                      \
      int rr = (wid * 2 + pp) * 8 + srow;                                   \
      LDSG(&kg[kvbase + (size_t)((KB) + rr) * 64 + (sc8 ^ (rr & 7)) * 8],   \
           &Ks[BUF][(wid * 2 + pp) * 512]);                                 \
      LDSG(&vtg[kvbase + (size_t)rr * 1024 + (KB) + (sc8 ^ (rr & 7)) * 8],  \
           &Vts[BUF][(wid * 2 + pp) * 512]);                                \
    } } while (0)

#define BODY(CB, KT) do {                                                   \
    if ((KT) + 1 < 16) {                                                    \
      REL_LOAD((CB) ^ 1, ((KT) + 1) * 64);                                  \
      STAGE((CB) ^ 1, ((KT) + 1) * 64);                                     \
    }                                                                       \
    f32x4 st[4] = {};                                                       \
    _Pragma("unroll") for (int ks = 0; ks < 2; ++ks)                        \
      _Pragma("unroll") for (int ct = 0; ct < 4; ++ct) {                    \
        int row = ct * 16 + ln15;                                           \
        bf16x8 kf = *(const bf16x8*)((const char*)&Ks[CB][0] + row * 128 +  \
                                     (((ks * 4 + lg) ^ (row & 7)) * 16));   \
        st[ct] = __builtin_amdgcn_mfma_f32_16x16x32_bf16(kf, qf[ks], st[ct],\
                                                         0, 0, 0);          \
      }                                                                     \
    float p[4][4]; float mt = -1e30f;                                       \
    const int kb_ = (KT) * 64;                                              \
    _Pragma("unroll") for (int ct = 0; ct < 4; ++ct) {                      \
      float4 mv = *(const float4*)&maskp[kb_ + ct * 16 + lg * 4];           \
      _Pragma("unroll") for (int j = 0; j < 4; ++j) {                       \
        float sv = st[ct][j] +                                              \
                   RELSC * (((const float*)&ra[CB][0][ct])[j] +             \
                            ((const float*)&ra[CB][1][ct])[j]) +            \
                   LOG2E * ((const float*)&mv)[j];                          \
        p[ct][j] = sv; mt = fmaxf(mt, sv);                                  \
      }                                                                     \
    }                                                                       \
    mt = fmaxf(mt, __shfl_xor(mt, 16, 64));                                 \
    mt = fmaxf(mt, __shfl_xor(mt, 32, 64));                                 \
    float mnew = fmaxf(mrun, mt);                                           \
    float sc_ = __builtin_amdgcn_exp2f(mrun - mnew);                        \
    mrun = mnew;                                                            \
    float lsum = 0.f;                                                       \
    _Pragma("unroll") for (int ct = 0; ct < 4; ++ct)                        \
      _Pragma("unroll") for (int j = 0; j < 4; ++j) {                       \
        float e = __builtin_amdgcn_exp2f(p[ct][j] - mnew);                  \
        p[ct][j] = e; lsum += e;                                            \
      }                                                                     \
    lsum += __shfl_xor(lsum, 16, 64);                                       \
    lsum += __shfl_xor(lsum, 32, 64);                                       \
    lrun = lrun * sc_ + lsum;                                               \
    _Pragma("unroll") for (int dt = 0; dt < 4; ++dt) accO[dt] *= sc_;       \
    __hip_bfloat16* Pw = &Ps[wid][0];                                       \
    _Pragma("unroll") for (int ct = 0; ct < 4; ++ct) {                      \
      union { ushort4 u; __hip_bfloat16 bb[4]; } w;                         \
      _Pragma("unroll") for (int j = 0; j < 4; ++j)                         \
        w.bb[j] = __float2bfloat16(p[ct][j]);                               \
      *(ushort4*)((char*)Pw + ln15 * 128 +                                  \
                  ((ct * 32 + lg * 8) ^ ((ln15 & 7) << 4))) = w.u;          \
    }                                                                       \
    bf16x8 pt[2];                                                           \
    pt[0] = *(const bf16x8*)((const char*)Pw + ln15 * 128 +                 \
                             ((lg * 16) ^ ((ln15 & 7) << 4)));              \
    pt[1] = *(const bf16x8*)((const char*)Pw + ln15 * 128 +                 \
                             ((64 + lg * 16) ^ ((ln15 & 7) << 4)));         \
    _Pragma("unroll") for (int ks = 0; ks < 2; ++ks)                        \
      _Pragma("unroll") for (int dt = 0; dt < 4; ++dt) {                    \
        int drow = dt * 16 + ln15;                                          \
        bf16x8 vf = *(const bf16x8*)((const char*)&Vts[CB][0] + drow * 128 +\
                                     (((ks * 4 + lg) ^ (drow & 7)) * 16));  \
        accO[dt] = __builtin_amdgcn_mfma_f32_16x16x32_bf16(vf, pt[ks],      \
                                                           accO[dt], 0, 0, 0);\
      }                                                                     \
    __syncthreads();                                                        \
  } while (0)

  REL_LOAD(0, 0);
  STAGE(0, 0);
  __syncthreads();

  for (int t = 0; t < 8; ++t) {
    BODY(0, 2 * t);
    BODY(1, 2 * t + 1);
  }

  // epilogue: lane holds ctx^T[d=dt*16+lg*4+j][q=q0+ln15]; out fp32 [b,s,C]
  float rl = 1.0f / lrun;
#pragma unroll
  for (int dt = 0; dt < 4; ++dt) {
    float4 o;
    o.x = accO[dt][0] * rl;
    o.y = accO[dt][1] * rl;
    o.z = accO[dt][2] * rl;
    o.w = accO[dt][3] * rl;
    *(float4*)&out[((size_t)(b * 1024 + q0 + ln15)) * 1024 + h * 64 +
                   dt * 16 + lg * 4] = o;
  }
}

// ---------------------------------------------------------------------------
extern "C" void kernel_launch(void* const* d_in, const int* in_sizes, int n_in,
                              void* d_out, int out_size, void* d_ws,
                              size_t ws_size, hipStream_t stream) {
  const float* hs   = (const float*)d_in[0];
  const float* mask = (const float*)d_in[1];
  const float* rel1 = (const float*)d_in[2];
  const float* rel2 = (const float*)d_in[3];
  const float* Wq   = (const float*)d_in[4];
  const float* bq   = (const float*)d_in[5];
  const float* Wk   = (const float*)d_in[6];
  const float* bk   = (const float*)d_in[7];
  const float* Wv   = (const float*)d_in[8];
  const float* bv   = (const float*)d_in[9];

  char* ws = (char*)d_ws;
  __hip_bfloat16* hbf = (__hip_bfloat16*)(ws);              // 8 MB
  __hip_bfloat16* wbf = (__hip_bfloat16*)(ws + 8388608);    // 6 MB
  __hip_bfloat16* qb  = (__hip_bfloat16*)(ws + 14680064);   // 8 MB
  __hip_bfloat16* kb  = (__hip_bfloat16*)(ws + 23068672);   // 8 MB
  __hip_bfloat16* vtb = (__hip_bfloat16*)(ws + 31457280);   // 8 MB (total 38)

  cvt_kernel<<<7168, 256, 0, stream>>>(hs, Wq, Wk, Wv, hbf, wbf);
  qkv_gemm<<<768, 256, 0, stream>>>(hbf, wbf, bq, bk, bv, qb, kb, vtb);
  attn_kernel<<<1024, 256, 0, stream>>>(qb, kb, vtb, rel1, rel2, mask,
                                        (float*)d_out);
}